// Round 4
// baseline (5495.030 us; speedup 1.0000x reference)
//
#include <hip/hip_runtime.h>
#include <stdint.h>

#define BATCH   4
#define NPTS    16384
#define NPOINT  1024
#define KNN     20
#define KSEL    21   // K+1, includes self

typedef unsigned long long u64;

// ---------------------------------------------------------------------------
// r22: STOP caching coords in registers — the allocator refuses to fund it.
// Evidence r19/r20/r21: attr(2,2)->92, attr(4,4)->52, launch_bounds(512,2)
// ->84 VGPRs; all spill the 128-VGPR point cache -> ~400KB/iter scratch
// traffic reaching HBM (FETCH 412MB for a 0.75MB input) -> 2.3us/iter.
// New fps design: only md[32] persists in VGPRs (32 regs); coords are
// STREAMED from global every iteration (L2-resident: 192KB/batch, one
// block per XCD, 4MB L2/XCD). Working set ~70 VGPRs < the ~84 the
// allocator grants -> no spill possible. An asm memory clobber at the top
// of each iteration stops LICM from hoisting the 96 loads back into
// registers (which would recreate the spill).
// FP expression tree, point<->thread mapping (idx = i*512+t), tie-break,
// and reduce are byte-identical to the validated r19/r21 kernels ->
// bitwise-identical outputs.
// knn_kernel unchanged from validated r19.
// ---------------------------------------------------------------------------
#define FPS_THREADS 512
#define PPT (NPTS / FPS_THREADS)     // 32 points per thread, strided
#define KNNT 512

// ===========================================================================
// Dispatch 1: FPS producer. One block per batch. 512 thr, md-only in regs.
// ===========================================================================
__global__ __launch_bounds__(FPS_THREADS)
void fps_kernel(const float* __restrict__ pts, float* __restrict__ out,
                int* __restrict__ slots) {
  const int b = blockIdx.x;
  const float* P = pts + (size_t)b * NPTS * 3;
  float* out_ind = out;                   // [B,NPOINT] (indices as float)
  float* out_q   = out + BATCH * NPOINT;  // [B,NPOINT,3]
  const int t = threadIdx.x;

  float md[PPT];
#pragma unroll
  for (int i = 0; i < PPT; ++i) md[i] = 1e10f;

  __shared__ float s_val[2][FPS_THREADS / 64];
  __shared__ int   s_idx[2][FPS_THREADS / 64];

  if (t == 0) {
    out_ind[b * NPOINT] = 0.0f;
    slots[b * NPOINT] = 0;
    float ax = P[0], ay = P[1], az = P[2];
    size_t o0 = (size_t)(b * NPOINT) * 3;
    out_q[o0 + 0] = ax; out_q[o0 + 1] = ay; out_q[o0 + 2] = az;
  }
  float qx = P[0], qy = P[1], qz = P[2];

  for (int it = 1; it < NPOINT; ++it) {
    // Force coord loads to re-execute this iteration (L2-resident stream)
    // instead of being hoisted into 96 live registers that would spill.
    __asm__ volatile("" ::: "memory");

    const int p = it & 1;
    float best = -1.0f;
    int bi = 0;
#pragma unroll
    for (int i = 0; i < PPT; ++i) {
      int idx = i * FPS_THREADS + t;
      float px = P[idx * 3 + 0];
      float py = P[idx * 3 + 1];
      float pz = P[idx * 3 + 2];
      float dx = __fsub_rn(px, qx);
      float dy = __fsub_rn(py, qy);
      float dz = __fsub_rn(pz, qz);
      float d  = __fadd_rn(__fadd_rn(__fmul_rn(dx, dx), __fmul_rn(dy, dy)),
                           __fmul_rn(dz, dz));
      float m = fminf(md[i], d);
      md[i] = m;
      bool g = (m > best);
      best = g ? m : best;
      bi   = g ? i : bi;
    }
    int bidx = bi * FPS_THREADS + t;

    // wave argmax reduce, tie -> lower global index
#pragma unroll
    for (int off = 32; off >= 1; off >>= 1) {
      float ov = __shfl_down(best, off);
      int   oi = __shfl_down(bidx, off);
      if (ov > best || (ov == best && oi < bidx)) { best = ov; bidx = oi; }
    }

    if ((t & 63) == 0) { s_val[p][t >> 6] = best; s_idx[p][t >> 6] = bidx; }
    __syncthreads();

    float bv = s_val[p][0];
    int   bx = s_idx[p][0];
#pragma unroll
    for (int w = 1; w < FPS_THREADS / 64; ++w) {
      float v = s_val[p][w];
      int   x = s_idx[p][w];
      if (v > bv || (v == bv && x < bx)) { bv = v; bx = x; }
    }

    qx = P[bx * 3 + 0];
    qy = P[bx * 3 + 1];
    qz = P[bx * 3 + 2];

    if (t == 0) {
      slots[b * NPOINT + it] = bx;
      out_ind[b * NPOINT + it] = (float)bx;
      size_t o = (size_t)(b * NPOINT + it) * 3;
      out_q[o + 0] = qx; out_q[o + 1] = qy; out_q[o + 2] = qz;
    }
  }
}

// ===========================================================================
// Dispatch 2: KNN consumers. Blocks 0..511 = knn_mid, 512..1023 = knn_out.
// One wave per query. Bodies unchanged from validated r19.
// ===========================================================================
__global__ __launch_bounds__(KNNT, 4)
void knn_kernel(const float* __restrict__ pts,
                const int* __restrict__ slots,
                float* __restrict__ out_nbr_mid,
                float* __restrict__ out_d_mid,
                float* __restrict__ out_nbr_out,
                float* __restrict__ out_d_out) {
  if (blockIdx.x < 512) {
    // ================= knn_mid role: one wave per query ===================
#pragma clang fp contract(off)
    const int kb   = blockIdx.x;
    const int wid  = kb * 8 + (threadIdx.x >> 6);
    const int lane = threadIdx.x & 63;
    const int b    = wid >> 10;
    const int qi   = wid & (NPOINT - 1);
    const float* C = pts + (size_t)b * NPTS * 3;

    const int widx = slots[b * NPOINT + qi];

    // q coords bit-identical to out_q (fps writes exactly P[widx])
    const float qx = C[widx * 3 + 0];
    const float qy = C[widx * 3 + 1];
    const float qz = C[widx * 3 + 2];
    const float qq = (qx * qx + qy * qy) + qz * qz;

    u64 best[KSEL];
#pragma unroll
    for (int j = 0; j < KSEL; ++j) best[j] = 0xFFFFFFFFFFFFFFFFull;

    for (int j = lane; j < NPTS; j += 64) {
      float px = C[j * 3 + 0], py = C[j * 3 + 1], pz = C[j * 3 + 2];
      float pp  = (px * px + py * py) + pz * pz;
      float dot = __builtin_fmaf(qz, pz, __builtin_fmaf(qy, py, qx * px));
      float d = (qq + pp) - 2.0f * dot;
      d = fmaxf(d, 0.0f);
      u64 key = ((u64)__float_as_uint(d) << 32) | (unsigned)j;
      if (key < best[KSEL - 1]) {
        u64 c = key;
#pragma unroll
        for (int s = 0; s < KSEL; ++s) {
          u64 o = best[s];
          bool l = c < o;
          u64 nb = l ? c : o;
          c = l ? o : c;
          best[s] = nb;
        }
      }
    }

    // LDS-free 64-way merge (validated r14/r16)
    int hp = 1;
    u64 head = best[0];
    int myK = -1, myIdx = 0;
#pragma unroll
    for (int r = 0; r < KSEL; ++r) {
      u64 v = head; int src = lane;
#pragma unroll
      for (int off = 32; off >= 1; off >>= 1) {
        u64 ov = __shfl_down(v, off);
        int os = __shfl_down(src, off);
        if (ov < v) { v = ov; src = os; }  // keys unique (idx embedded)
      }
      v   = __shfl(v, 0);
      src = __shfl(src, 0);
      if (r >= 1 && lane == r - 1) {       // drop r==0 (self)
        myIdx = (int)(unsigned)(v & 0xFFFFFFFFull);
        myK = r - 1;
      }
      if (lane == src) {
        u64 h = 0xFFFFFFFFFFFFFFFFull;
#pragma unroll
        for (int s = 1; s < KSEL; ++s) if (hp == s) h = best[s];
        head = h;
        hp++;
      }
    }

    if (myK >= 0) {
      size_t o = (size_t)(b * NPOINT + qi) * KNN + myK;
      out_nbr_mid[o] = (float)myIdx;
      float sx = C[myIdx * 3 + 0], sy = C[myIdx * 3 + 1],
            sz = C[myIdx * 3 + 2];
      out_d_mid[o * 3 + 0] = qx - sx;
      out_d_mid[o * 3 + 1] = qy - sy;
      out_d_mid[o * 3 + 2] = qz - sz;
    }
  } else {
    // ================= knn_out role: one wave per query ===================
#pragma clang fp contract(off)
    const int kb   = blockIdx.x - 512;
    const int wid  = kb * 8 + (threadIdx.x >> 6);
    const int lane = threadIdx.x & 63;
    const int b    = wid >> 10;
    const int qi   = wid & (NPOINT - 1);
    const float* C = pts + (size_t)b * NPTS * 3;

    // my query's point index
    const int wq = slots[b * NPOINT + qi];
    const float qx = C[wq * 3 + 0];
    const float qy = C[wq * 3 + 1];
    const float qz = C[wq * 3 + 2];
    const float qq = (qx * qx + qy * qy) + qz * qz;

    // candidate point indices for my 16 positions (coalesced slot reads)
    int wj[NPOINT / 64];
#pragma unroll
    for (int u = 0; u < NPOINT / 64; ++u) {
      wj[u] = slots[b * NPOINT + u * 64 + lane];
    }

    u64 best[KSEL];
#pragma unroll
    for (int j = 0; j < KSEL; ++j) best[j] = 0xFFFFFFFFFFFFFFFFull;

#pragma unroll
    for (int u = 0; u < NPOINT / 64; ++u) {
      int j = u * 64 + lane;               // candidate POSITION (the key idx)
      int w = wj[u];
      float px = C[w * 3 + 0], py = C[w * 3 + 1], pz = C[w * 3 + 2];
      float pp  = (px * px + py * py) + pz * pz;
      float dot = __builtin_fmaf(qz, pz, __builtin_fmaf(qy, py, qx * px));
      float d = (qq + pp) - 2.0f * dot;
      d = fmaxf(d, 0.0f);
      u64 key = ((u64)__float_as_uint(d) << 32) | (unsigned)j;
      if (key < best[KSEL - 1]) {
        u64 c = key;
#pragma unroll
        for (int s = 0; s < KSEL; ++s) {
          u64 o = best[s];
          bool l = c < o;
          u64 nb = l ? c : o;
          c = l ? o : c;
          best[s] = nb;
        }
      }
    }

    // LDS-free 64-way merge (validated r14/r16)
    int hp = 1;
    u64 head = best[0];
    int myK = -1, myIdx = 0;
#pragma unroll
    for (int r = 0; r < KSEL; ++r) {
      u64 v = head; int src = lane;
#pragma unroll
      for (int off = 32; off >= 1; off >>= 1) {
        u64 ov = __shfl_down(v, off);
        int os = __shfl_down(src, off);
        if (ov < v) { v = ov; src = os; }
      }
      v   = __shfl(v, 0);
      src = __shfl(src, 0);
      if (r >= 1 && lane == r - 1) {
        myIdx = (int)(unsigned)(v & 0xFFFFFFFFull);
        myK = r - 1;
      }
      if (lane == src) {
        u64 h = 0xFFFFFFFFFFFFFFFFull;
#pragma unroll
        for (int s = 1; s < KSEL; ++s) if (hp == s) h = best[s];
        head = h;
        hp++;
      }
    }

    if (myK >= 0) {
      size_t o = (size_t)(b * NPOINT + qi) * KNN + myK;
      out_nbr_out[o] = (float)myIdx;
      const int w = slots[b * NPOINT + myIdx];
      float sx = C[w * 3 + 0], sy = C[w * 3 + 1], sz = C[w * 3 + 2];
      out_d_out[o * 3 + 0] = qx - sx;
      out_d_out[o * 3 + 1] = qy - sy;
      out_d_out[o * 3 + 2] = qz - sz;
    }
  }
}

// ---------------------------------------------------------------------------
extern "C" void kernel_launch(void* const* d_in, const int* in_sizes, int n_in,
                              void* d_out, int out_size, void* d_ws,
                              size_t ws_size, hipStream_t stream) {
  (void)in_sizes; (void)n_in; (void)out_size; (void)ws_size;
  const float* pts = (const float*)d_in[0];
  float* out = (float*)d_out;

  // ws layout: slots only — 4 x 1024 x 4B = 16 KB (int winner indices)
  int* slots = (int*)d_ws;

  // output layout (floats): [xyz_ind | xyz_query | nbr_mid | d_mid | nbr_out | d_out]
  float* out_nbr_mid = out + (size_t)BATCH * NPOINT * 4;
  float* out_d_mid   = out_nbr_mid + (size_t)BATCH * NPOINT * KNN;
  float* out_nbr_out = out_d_mid + (size_t)BATCH * NPOINT * KNN * 3;
  float* out_d_out   = out_nbr_out + (size_t)BATCH * NPOINT * KNN;

  hipLaunchKernelGGL(fps_kernel, dim3(BATCH), dim3(FPS_THREADS), 0, stream,
                     pts, out, slots);
  hipLaunchKernelGGL(knn_kernel, dim3(1024), dim3(KNNT), 0, stream,
                     pts, slots, out_nbr_mid, out_d_mid, out_nbr_out,
                     out_d_out);
}

// Round 5
// 3543.210 us; speedup vs baseline: 1.5509x; 1.5509x over previous
//
#include <hip/hip_runtime.h>
#include <stdint.h>

#define BATCH   4
#define NPTS    16384
#define NPOINT  1024
#define KNN     20
#define KSEL    21   // K+1, includes self

typedef unsigned long long u64;

// ---------------------------------------------------------------------------
// r23: LDS-resident FPS. Session facts driving this design:
//  - allocator caps this kernel at ~84-92 VGPRs regardless of
//    waves_per_eu / launch_bounds (r19/r20/r21) -> a 128-VGPR coord cache
//    ALWAYS spills (~400KB/iter scratch -> 2.3us/iter).
//  - per-iteration global streaming is latency-poisoned (r22: 5.0us/iter,
//    VALUBusy 0.49%).
// Fix: coords live in LDS (resident, ~640cy/iter BW, separate pipe from
// VALU). 160KB/CU fits 26 of 32 strides (13312 pts, 156KB) packed as
// float4(x,y|x,y) + float2(z|z) pairs -> 13 b128 + 13 b64 reads/thread,
// conflict-free. The remaining 6 strides (3072 pts, 18 dword loads/thread,
// L1/L2-hot) are issued BEFORE the LDS scan so latency hides under it;
// opaque base pointer prevents LICM from hoisting them into persistent
// registers. Persistent regs: md[32] only -> ~75 total < 84 grant -> no
// spill. FP exprs, scan order (i=0..31 ascending), tie-break, and reduce
// byte-identical to validated r19/r21 -> bitwise-identical outputs.
// knn_kernel unchanged from validated r19.
// ---------------------------------------------------------------------------
#define FPS_THREADS 512
#define NSTR       32                      // strides = points per thread
#define LPAIRS     13                      // float4-pairs in LDS
#define LDS_STR    (2 * LPAIRS)            // 26 strides in LDS
#define STREAM_STR (NSTR - LDS_STR)        // 6 strides streamed
#define LDS_PTS    (LDS_STR * FPS_THREADS) // 13312 points
#define DYN_LDS_BYTES (LDS_PTS * 12)       // 159744 B (+128 static < 160K)
#define KNNT 512

// ===========================================================================
// Dispatch 1: FPS producer. One block per batch. 512 thr.
// ===========================================================================
__global__ __launch_bounds__(FPS_THREADS)
void fps_kernel(const float* __restrict__ pts, float* __restrict__ out,
                int* __restrict__ slots) {
  const int b = blockIdx.x;
  const float* P = pts + (size_t)b * NPTS * 3;
  float* out_ind = out;                   // [B,NPOINT] (indices as float)
  float* out_q   = out + BATCH * NPOINT;  // [B,NPOINT,3]
  const int t = threadIdx.x;

  extern __shared__ float lds[];
  float4* sxy2 = (float4*)lds;                                   // 106496 B
  float2* sz2  = (float2*)(lds + (size_t)LPAIRS * FPS_THREADS * 4); // 53248 B

  // One-time fill: pair strides (2u, 2u+1). Same bit values as global.
#pragma unroll
  for (int u = 0; u < LPAIRS; ++u) {
    int ia = (2 * u) * FPS_THREADS + t;
    int ib = ia + FPS_THREADS;
    float4 c;
    c.x = P[ia * 3 + 0]; c.y = P[ia * 3 + 1];
    c.z = P[ib * 3 + 0]; c.w = P[ib * 3 + 1];
    sxy2[u * FPS_THREADS + t] = c;
    float2 zz;
    zz.x = P[ia * 3 + 2]; zz.y = P[ib * 3 + 2];
    sz2[u * FPS_THREADS + t] = zz;
  }

  float md[NSTR];
#pragma unroll
  for (int i = 0; i < NSTR; ++i) md[i] = 1e10f;

  __shared__ float s_val[2][FPS_THREADS / 64];
  __shared__ int   s_idx[2][FPS_THREADS / 64];

  if (t == 0) {
    out_ind[b * NPOINT] = 0.0f;
    slots[b * NPOINT] = 0;
    float ax = P[0], ay = P[1], az = P[2];
    size_t o0 = (size_t)(b * NPOINT) * 3;
    out_q[o0 + 0] = ax; out_q[o0 + 1] = ay; out_q[o0 + 2] = az;
  }
  float qx = P[0], qy = P[1], qz = P[2];

  __syncthreads();   // LDS fill visible to all waves

  for (int it = 1; it < NPOINT; ++it) {
    const int p = it & 1;
    float best = -1.0f;
    int bi = 0;

    // Issue the 18 streamed loads FIRST (latency hides under LDS scan).
    // Opaque base stops LICM from hoisting them into persistent registers.
    const float* Pv = P;
    __asm__ volatile("" : "+v"(Pv));
    float gx[STREAM_STR], gy[STREAM_STR], gz[STREAM_STR];
#pragma unroll
    for (int u = 0; u < STREAM_STR; ++u) {
      int idx = (LDS_STR + u) * FPS_THREADS + t;
      gx[u] = Pv[idx * 3 + 0];
      gy[u] = Pv[idx * 3 + 1];
      gz[u] = Pv[idx * 3 + 2];
    }

    // LDS part: strides 0..25 in ascending order (bitwise-identical tree).
#pragma unroll
    for (int u = 0; u < LPAIRS; ++u) {
      float4 c  = sxy2[u * FPS_THREADS + t];
      float2 zz = sz2[u * FPS_THREADS + t];
      {
        float dx = __fsub_rn(c.x, qx);
        float dy = __fsub_rn(c.y, qy);
        float dz = __fsub_rn(zz.x, qz);
        float d  = __fadd_rn(__fadd_rn(__fmul_rn(dx, dx), __fmul_rn(dy, dy)),
                             __fmul_rn(dz, dz));
        float m = fminf(md[2 * u], d);
        md[2 * u] = m;
        bool g = (m > best);
        best = g ? m : best;
        bi   = g ? (2 * u) : bi;
      }
      {
        float dx = __fsub_rn(c.z, qx);
        float dy = __fsub_rn(c.w, qy);
        float dz = __fsub_rn(zz.y, qz);
        float d  = __fadd_rn(__fadd_rn(__fmul_rn(dx, dx), __fmul_rn(dy, dy)),
                             __fmul_rn(dz, dz));
        float m = fminf(md[2 * u + 1], d);
        md[2 * u + 1] = m;
        bool g = (m > best);
        best = g ? m : best;
        bi   = g ? (2 * u + 1) : bi;
      }
    }

    // Streamed part: strides 26..31 (same order/exprs as validated kernel).
#pragma unroll
    for (int u = 0; u < STREAM_STR; ++u) {
      int i = LDS_STR + u;
      float dx = __fsub_rn(gx[u], qx);
      float dy = __fsub_rn(gy[u], qy);
      float dz = __fsub_rn(gz[u], qz);
      float d  = __fadd_rn(__fadd_rn(__fmul_rn(dx, dx), __fmul_rn(dy, dy)),
                           __fmul_rn(dz, dz));
      float m = fminf(md[i], d);
      md[i] = m;
      bool g = (m > best);
      best = g ? m : best;
      bi   = g ? i : bi;
    }

    int bidx = bi * FPS_THREADS + t;

    // wave argmax reduce, tie -> lower global index (validated)
#pragma unroll
    for (int off = 32; off >= 1; off >>= 1) {
      float ov = __shfl_down(best, off);
      int   oi = __shfl_down(bidx, off);
      if (ov > best || (ov == best && oi < bidx)) { best = ov; bidx = oi; }
    }

    if ((t & 63) == 0) { s_val[p][t >> 6] = best; s_idx[p][t >> 6] = bidx; }
    __syncthreads();

    float bv = s_val[p][0];
    int   bx = s_idx[p][0];
#pragma unroll
    for (int w = 1; w < FPS_THREADS / 64; ++w) {
      float v = s_val[p][w];
      int   x = s_idx[p][w];
      if (v > bv || (v == bv && x < bx)) { bv = v; bx = x; }
    }

    qx = P[bx * 3 + 0];
    qy = P[bx * 3 + 1];
    qz = P[bx * 3 + 2];

    if (t == 0) {
      slots[b * NPOINT + it] = bx;
      out_ind[b * NPOINT + it] = (float)bx;
      size_t o = (size_t)(b * NPOINT + it) * 3;
      out_q[o + 0] = qx; out_q[o + 1] = qy; out_q[o + 2] = qz;
    }
  }
}

// ===========================================================================
// Dispatch 2: KNN consumers. Blocks 0..511 = knn_mid, 512..1023 = knn_out.
// One wave per query. Bodies unchanged from validated r19.
// ===========================================================================
__global__ __launch_bounds__(KNNT, 4)
void knn_kernel(const float* __restrict__ pts,
                const int* __restrict__ slots,
                float* __restrict__ out_nbr_mid,
                float* __restrict__ out_d_mid,
                float* __restrict__ out_nbr_out,
                float* __restrict__ out_d_out) {
  if (blockIdx.x < 512) {
    // ================= knn_mid role: one wave per query ===================
#pragma clang fp contract(off)
    const int kb   = blockIdx.x;
    const int wid  = kb * 8 + (threadIdx.x >> 6);
    const int lane = threadIdx.x & 63;
    const int b    = wid >> 10;
    const int qi   = wid & (NPOINT - 1);
    const float* C = pts + (size_t)b * NPTS * 3;

    const int widx = slots[b * NPOINT + qi];

    // q coords bit-identical to out_q (fps writes exactly P[widx])
    const float qx = C[widx * 3 + 0];
    const float qy = C[widx * 3 + 1];
    const float qz = C[widx * 3 + 2];
    const float qq = (qx * qx + qy * qy) + qz * qz;

    u64 best[KSEL];
#pragma unroll
    for (int j = 0; j < KSEL; ++j) best[j] = 0xFFFFFFFFFFFFFFFFull;

    for (int j = lane; j < NPTS; j += 64) {
      float px = C[j * 3 + 0], py = C[j * 3 + 1], pz = C[j * 3 + 2];
      float pp  = (px * px + py * py) + pz * pz;
      float dot = __builtin_fmaf(qz, pz, __builtin_fmaf(qy, py, qx * px));
      float d = (qq + pp) - 2.0f * dot;
      d = fmaxf(d, 0.0f);
      u64 key = ((u64)__float_as_uint(d) << 32) | (unsigned)j;
      if (key < best[KSEL - 1]) {
        u64 c = key;
#pragma unroll
        for (int s = 0; s < KSEL; ++s) {
          u64 o = best[s];
          bool l = c < o;
          u64 nb = l ? c : o;
          c = l ? o : c;
          best[s] = nb;
        }
      }
    }

    // LDS-free 64-way merge (validated r14/r16)
    int hp = 1;
    u64 head = best[0];
    int myK = -1, myIdx = 0;
#pragma unroll
    for (int r = 0; r < KSEL; ++r) {
      u64 v = head; int src = lane;
#pragma unroll
      for (int off = 32; off >= 1; off >>= 1) {
        u64 ov = __shfl_down(v, off);
        int os = __shfl_down(src, off);
        if (ov < v) { v = ov; src = os; }  // keys unique (idx embedded)
      }
      v   = __shfl(v, 0);
      src = __shfl(src, 0);
      if (r >= 1 && lane == r - 1) {       // drop r==0 (self)
        myIdx = (int)(unsigned)(v & 0xFFFFFFFFull);
        myK = r - 1;
      }
      if (lane == src) {
        u64 h = 0xFFFFFFFFFFFFFFFFull;
#pragma unroll
        for (int s = 1; s < KSEL; ++s) if (hp == s) h = best[s];
        head = h;
        hp++;
      }
    }

    if (myK >= 0) {
      size_t o = (size_t)(b * NPOINT + qi) * KNN + myK;
      out_nbr_mid[o] = (float)myIdx;
      float sx = C[myIdx * 3 + 0], sy = C[myIdx * 3 + 1],
            sz = C[myIdx * 3 + 2];
      out_d_mid[o * 3 + 0] = qx - sx;
      out_d_mid[o * 3 + 1] = qy - sy;
      out_d_mid[o * 3 + 2] = qz - sz;
    }
  } else {
    // ================= knn_out role: one wave per query ===================
#pragma clang fp contract(off)
    const int kb   = blockIdx.x - 512;
    const int wid  = kb * 8 + (threadIdx.x >> 6);
    const int lane = threadIdx.x & 63;
    const int b    = wid >> 10;
    const int qi   = wid & (NPOINT - 1);
    const float* C = pts + (size_t)b * NPTS * 3;

    // my query's point index
    const int wq = slots[b * NPOINT + qi];
    const float qx = C[wq * 3 + 0];
    const float qy = C[wq * 3 + 1];
    const float qz = C[wq * 3 + 2];
    const float qq = (qx * qx + qy * qy) + qz * qz;

    // candidate point indices for my 16 positions (coalesced slot reads)
    int wj[NPOINT / 64];
#pragma unroll
    for (int u = 0; u < NPOINT / 64; ++u) {
      wj[u] = slots[b * NPOINT + u * 64 + lane];
    }

    u64 best[KSEL];
#pragma unroll
    for (int j = 0; j < KSEL; ++j) best[j] = 0xFFFFFFFFFFFFFFFFull;

#pragma unroll
    for (int u = 0; u < NPOINT / 64; ++u) {
      int j = u * 64 + lane;               // candidate POSITION (the key idx)
      int w = wj[u];
      float px = C[w * 3 + 0], py = C[w * 3 + 1], pz = C[w * 3 + 2];
      float pp  = (px * px + py * py) + pz * pz;
      float dot = __builtin_fmaf(qz, pz, __builtin_fmaf(qy, py, qx * px));
      float d = (qq + pp) - 2.0f * dot;
      d = fmaxf(d, 0.0f);
      u64 key = ((u64)__float_as_uint(d) << 32) | (unsigned)j;
      if (key < best[KSEL - 1]) {
        u64 c = key;
#pragma unroll
        for (int s = 0; s < KSEL; ++s) {
          u64 o = best[s];
          bool l = c < o;
          u64 nb = l ? c : o;
          c = l ? o : c;
          best[s] = nb;
        }
      }
    }

    // LDS-free 64-way merge (validated r14/r16)
    int hp = 1;
    u64 head = best[0];
    int myK = -1, myIdx = 0;
#pragma unroll
    for (int r = 0; r < KSEL; ++r) {
      u64 v = head; int src = lane;
#pragma unroll
      for (int off = 32; off >= 1; off >>= 1) {
        u64 ov = __shfl_down(v, off);
        int os = __shfl_down(src, off);
        if (ov < v) { v = ov; src = os; }
      }
      v   = __shfl(v, 0);
      src = __shfl(src, 0);
      if (r >= 1 && lane == r - 1) {
        myIdx = (int)(unsigned)(v & 0xFFFFFFFFull);
        myK = r - 1;
      }
      if (lane == src) {
        u64 h = 0xFFFFFFFFFFFFFFFFull;
#pragma unroll
        for (int s = 1; s < KSEL; ++s) if (hp == s) h = best[s];
        head = h;
        hp++;
      }
    }

    if (myK >= 0) {
      size_t o = (size_t)(b * NPOINT + qi) * KNN + myK;
      out_nbr_out[o] = (float)myIdx;
      const int w = slots[b * NPOINT + myIdx];
      float sx = C[w * 3 + 0], sy = C[w * 3 + 1], sz = C[w * 3 + 2];
      out_d_out[o * 3 + 0] = qx - sx;
      out_d_out[o * 3 + 1] = qy - sy;
      out_d_out[o * 3 + 2] = qz - sz;
    }
  }
}

// ---------------------------------------------------------------------------
extern "C" void kernel_launch(void* const* d_in, const int* in_sizes, int n_in,
                              void* d_out, int out_size, void* d_ws,
                              size_t ws_size, hipStream_t stream) {
  (void)in_sizes; (void)n_in; (void)out_size; (void)ws_size;
  const float* pts = (const float*)d_in[0];
  float* out = (float*)d_out;

  // ws layout: slots only — 4 x 1024 x 4B = 16 KB (int winner indices)
  int* slots = (int*)d_ws;

  // output layout (floats): [xyz_ind | xyz_query | nbr_mid | d_mid | nbr_out | d_out]
  float* out_nbr_mid = out + (size_t)BATCH * NPOINT * 4;
  float* out_d_mid   = out_nbr_mid + (size_t)BATCH * NPOINT * KNN;
  float* out_nbr_out = out_d_mid + (size_t)BATCH * NPOINT * KNN * 3;
  float* out_d_out   = out_nbr_out + (size_t)BATCH * NPOINT * KNN;

  // Opt in to >64KB dynamic LDS (one-time host-side attribute, not a
  // stream op -> graph-capture safe).
  static int lds_set = 0;
  if (!lds_set) {
    (void)hipFuncSetAttribute((const void*)fps_kernel,
                              hipFuncAttributeMaxDynamicSharedMemorySize,
                              DYN_LDS_BYTES);
    lds_set = 1;
  }

  hipLaunchKernelGGL(fps_kernel, dim3(BATCH), dim3(FPS_THREADS),
                     DYN_LDS_BYTES, stream, pts, out, slots);
  hipLaunchKernelGGL(knn_kernel, dim3(1024), dim3(KNNT), 0, stream,
                     pts, slots, out_nbr_mid, out_d_mid, out_nbr_out,
                     out_d_out);
}